// Round 1
// baseline (137.224 us; speedup 1.0000x reference)
//
#include <hip/hip_runtime.h>

#define NB 4          // batches per block
#define LN_EPS 1e-3f

static __device__ __forceinline__ float sgnf(float x) {
    return (x > 0.f) ? 1.f : ((x < 0.f) ? -1.f : 0.f);
}
static __device__ __forceinline__ float siluf(float x) {
    return x / (1.f + __expf(-x));
}

// ws layout (floats): [0, 2176)  h_pad[2][1088]   (zero-padded filter)
//                     [2176, 4224) sp[2][1024]    (processed symbols)

// ---------------- prep: build h_pad and sp (one block) ----------------
__global__ __launch_bounds__(256) void hd_prep(
    const float* __restrict__ h, const float* __restrict__ symbols,
    const float* __restrict__ gamma, const float* __restrict__ beta,
    float* __restrict__ ws)
{
    __shared__ float h_pad[2][1088];
    __shared__ float x_s[2][64];
    __shared__ float red[4][2];
    const int t = threadIdx.x;

    for (int idx = t; idx < 2 * 1088; idx += 256) {
        const int c = idx / 1088, j = idx - c * 1088;
        float v = 0.f;
        if (j >= 63 && j <= 1023) v = h[c * 961 + (j - 63)];
        h_pad[c][j] = v;
        ws[idx] = v;
    }
    if (t < 128) x_s[t >> 6][t & 63] = symbols[t];
    __syncthreads();

    const int c = t >> 7, tt = t & 127;
    const int lane = t & 63, wid = t >> 6;
    const int jbase = 1023 - tt;   // h_pad index = 1023 - o + i,  o = tt + 128k

    float acc[8];
    #pragma unroll
    for (int k = 0; k < 8; ++k) acc[k] = 0.f;

    #pragma unroll 8
    for (int i = 0; i < 64; ++i) {
        const float xv = x_s[c][i];
        #pragma unroll
        for (int k = 0; k < 8; ++k)
            acc[k] = fmaf(xv, h_pad[c][jbase + i - 128 * k], acc[k]);
    }

    float ps = 0.f, pq = 0.f;
    #pragma unroll
    for (int k = 0; k < 8; ++k) { ps += acc[k]; pq += acc[k] * acc[k]; }
    #pragma unroll
    for (int off = 32; off; off >>= 1) {
        ps += __shfl_xor(ps, off);
        pq += __shfl_xor(pq, off);
    }
    if (lane == 0) { red[wid][0] = ps; red[wid][1] = pq; }
    __syncthreads();

    const float sum = red[2 * c][0] + red[2 * c + 1][0];
    const float sq  = red[2 * c][1] + red[2 * c + 1][1];
    const float mu  = sum * (1.f / 1024.f);
    float var = sq * (1.f / 1024.f) - mu * mu;
    var = fmaxf(var, 0.f);
    const float rs = rsqrtf(var + LN_EPS);

    #pragma unroll
    for (int k = 0; k < 8; ++k) {
        const int d = tt + 128 * k;
        const float ln = (acc[k] - mu) * rs * gamma[d] + beta[d];
        ws[2176 + c * 1024 + d] = siluf(ln);
    }
}

// ---------------- main fused kernel: NB batches per block ----------------
__global__ __launch_bounds__(256) void hd_main(
    const float* __restrict__ values,
    const float* __restrict__ gamma, const float* __restrict__ beta,
    const float* __restrict__ ws, float* __restrict__ out)
{
    __shared__ float h_pad[2][1088];
    __shared__ float x_s[NB][2][64];
    __shared__ float vp_s[NB][2][1024];
    __shared__ float red[4][NB][2];
    __shared__ float S_s[NB][2][2];

    const int t = threadIdx.x;
    const int b0 = blockIdx.x * NB;

    for (int idx = t; idx < 2 * 1088; idx += 256)
        (&h_pad[0][0])[idx] = ws[idx];
    for (int idx = t; idx < NB * 128; idx += 256)
        (&x_s[0][0][0])[idx] = values[(size_t)b0 * 128 + idx];
    __syncthreads();

    const int c = t >> 7, tt = t & 127;      // waves 0,1 -> c=0 ; waves 2,3 -> c=1
    const int lane = t & 63, wid = t >> 6;
    const int jbase = 1023 - tt;

    // ---- grouped conv: thread owns outputs d = tt + 128k, k=0..7, for NB batches
    float acc[NB][8];
    #pragma unroll
    for (int b = 0; b < NB; ++b)
        #pragma unroll
        for (int k = 0; k < 8; ++k) acc[b][k] = 0.f;

    #pragma unroll 4
    for (int i = 0; i < 64; ++i) {
        float hv[8];
        #pragma unroll
        for (int k = 0; k < 8; ++k) hv[k] = h_pad[c][jbase + i - 128 * k];
        #pragma unroll
        for (int b = 0; b < NB; ++b) {
            const float xv = x_s[b][c][i];
            #pragma unroll
            for (int k = 0; k < 8; ++k) acc[b][k] = fmaf(xv, hv[k], acc[b][k]);
        }
    }

    // ---- LayerNorm reductions (per batch, per channel: 128 threads = 2 waves)
    float ps[NB], pq[NB];
    #pragma unroll
    for (int b = 0; b < NB; ++b) {
        ps[b] = 0.f; pq[b] = 0.f;
        #pragma unroll
        for (int k = 0; k < 8; ++k) { ps[b] += acc[b][k]; pq[b] += acc[b][k] * acc[b][k]; }
    }
    #pragma unroll
    for (int off = 32; off; off >>= 1) {
        #pragma unroll
        for (int b = 0; b < NB; ++b) {
            ps[b] += __shfl_xor(ps[b], off);
            pq[b] += __shfl_xor(pq[b], off);
        }
    }
    if (lane == 0) {
        #pragma unroll
        for (int b = 0; b < NB; ++b) { red[wid][b][0] = ps[b]; red[wid][b][1] = pq[b]; }
    }
    __syncthreads();

    float gk[8], bk[8];
    #pragma unroll
    for (int k = 0; k < 8; ++k) {
        const int d = tt + 128 * k;
        gk[k] = gamma[d]; bk[k] = beta[d];
    }

    #pragma unroll
    for (int b = 0; b < NB; ++b) {
        const float sum = red[2 * c][b][0] + red[2 * c + 1][b][0];
        const float sq  = red[2 * c][b][1] + red[2 * c + 1][b][1];
        const float mu  = sum * (1.f / 1024.f);
        float var = sq * (1.f / 1024.f) - mu * mu;
        var = fmaxf(var, 0.f);
        const float rs = rsqrtf(var + LN_EPS);
        #pragma unroll
        for (int k = 0; k < 8; ++k) {
            const float v = siluf((acc[b][k] - mu) * rs * gk[k] + bk[k]);
            acc[b][k] = v;                      // acc now holds vp for (b, c, d)
            vp_s[b][c][tt + 128 * k] = v;
        }
    }

    // sp rows (both a=0,1) for this thread's 8 d positions
    float spreg[2][8];
    #pragma unroll
    for (int a = 0; a < 2; ++a)
        #pragma unroll
        for (int k = 0; k < 8; ++k)
            spreg[a][k] = ws[2176 + a * 1024 + tt + 128 * k];

    __syncthreads();   // vp_s complete; red free for reuse

    // ---- S[b][a][c] partials over this thread's 8 d's
    float pa[NB][2];
    #pragma unroll
    for (int b = 0; b < NB; ++b) {
        #pragma unroll
        for (int a = 0; a < 2; ++a) {
            float s = 0.f;
            #pragma unroll
            for (int k = 0; k < 8; ++k)
                s += sgnf(acc[b][k]) * sgnf(acc[b][k] + spreg[a][k]);
            pa[b][a] = s;
        }
    }
    #pragma unroll
    for (int off = 32; off; off >>= 1) {
        #pragma unroll
        for (int b = 0; b < NB; ++b) {
            pa[b][0] += __shfl_xor(pa[b][0], off);
            pa[b][1] += __shfl_xor(pa[b][1], off);
        }
    }
    if (lane == 0) {
        #pragma unroll
        for (int b = 0; b < NB; ++b) { red[wid][b][0] = pa[b][0]; red[wid][b][1] = pa[b][1]; }
    }
    __syncthreads();
    if (tt == 0) {
        #pragma unroll
        for (int b = 0; b < NB; ++b)
            #pragma unroll
            for (int a = 0; a < 2; ++a)
                S_s[b][a][c] = (red[2 * c][b][a] + red[2 * c + 1][b][a]) * (1.f / 1024.f);
    }
    __syncthreads();

    // ---- softmax (over c, 2-wide) + attn + silu; thread now owns row a = c
    const int a = c;
    #pragma unroll
    for (int b = 0; b < NB; ++b) {
        const float s0 = S_s[b][a][0], s1 = S_s[b][a][1];
        const float m = fmaxf(s0, s1);
        const float e0 = __expf(s0 - m), e1 = __expf(s1 - m);
        const float inv = 1.f / (e0 + e1);
        const float p0 = e0 * inv, p1 = e1 * inv;
        float* orow = out + ((size_t)(b0 + b) * 2 + a) * 1024;
        #pragma unroll
        for (int k = 0; k < 8; ++k) {
            const int d = tt + 128 * k;
            const float attn = p0 * vp_s[b][0][d] + p1 * vp_s[b][1][d];
            orow[d] = siluf(attn * spreg[a][k]);
        }
    }
}

extern "C" void kernel_launch(void* const* d_in, const int* in_sizes, int n_in,
                              void* d_out, int out_size, void* d_ws, size_t ws_size,
                              hipStream_t stream) {
    const float* values  = (const float*)d_in[0];
    const float* h       = (const float*)d_in[1];
    const float* gamma   = (const float*)d_in[2];
    const float* beta    = (const float*)d_in[3];
    const float* symbols = (const float*)d_in[4];
    float* out = (float*)d_out;
    float* ws  = (float*)d_ws;

    const int B = in_sizes[0] / 128;   // 16384

    hipLaunchKernelGGL(hd_prep, dim3(1), dim3(256), 0, stream,
                       h, symbols, gamma, beta, ws);
    hipLaunchKernelGGL(hd_main, dim3(B / NB), dim3(256), 0, stream,
                       values, gamma, beta, ws, out);
}